// Round 1
// 897.864 us; speedup vs baseline: 1.0876x; 1.0876x over previous
//
#include <hip/hip_runtime.h>

// LearnableChannelSplit, FUSED: 1x1 conv (512->128) -> ReLU -> 1x1 conv
// (128->2) -> softmax(2ch) -> x0 = x*m0, x1 = x*m1, in ONE kernel.
// Rationale: the old 2-kernel version read x (302 MB) from HBM twice; fusing
// lets phase 3 re-read the block's own 256 KB while it is still L2/L3-hot,
// and nontemporal stores keep the 604 MB of streaming writes from evicting it.
// Outputs concatenated: x0 (75497472), x1 (75497472), m (294912), all fp32.

#define BB   16
#define CC   512
#define HH   96
#define WW   96
#define HWP  (HH * WW)          // 9216
#define CHN  128
#define XSZ  (BB * CC * HWP)    // 75497472

#define KC   32                 // K-chunk (input channels per LDS stage)
#define PXT  128                // pixels per block

typedef float v4f __attribute__((ext_vector_type(4)));

// Block: 256 threads, tile = 128 pixels x 128 hidden channels.
// Phase 1 (unchanged from prev best): thread t owns pixels px0..px0+7
// (px0=(t&15)*8) x hidden o0..o0+7 (o0=(t>>4)*8) -> 8x8 fp32 register tile,
// K staged through LDS in chunks of 32. Epilogue: +b1, ReLU, dot with w2 rows
// -> partial logits -> LDS reduction over 16 o-groups -> softmax.
// Phase 2: broadcast m0/m1 via LDS (overlays ws).
// Phase 3: re-read x (reverse channel order = most-recently-staged first,
// so it hits L2/L3), multiply, nontemporal-store x0/x1.
__global__ __launch_bounds__(256) void fused_split_kernel(
    const float* __restrict__ x, const float* __restrict__ w1,
    const float* __restrict__ b1, const float* __restrict__ w2,
    const float* __restrict__ b2, float* __restrict__ out0,
    float* __restrict__ out1, float* __restrict__ mout)
{
    __shared__ __align__(16) float smem[KC * PXT + KC * CHN];  // 32 KB
    float* xs  = smem;             // [KC][PXT]
    float* ws  = smem + KC * PXT;  // [KC][CHN]  (w1 transposed: [c][o])
    float* red = smem;             // [16][PXT][2] overlays xs after K-loop
    float* sm  = smem + KC * PXT;  // [2][PXT] m broadcast, overlays ws

    const int t   = threadIdx.x;
    const int p0  = blockIdx.x * PXT;     // 9216 % 128 == 0 -> never straddles b
    const int b   = p0 / HWP;
    const int hw0 = p0 - b * HWP;

    const int px0 = (t & 15) * 8;
    const int og  = t >> 4;               // 0..15
    const int o0  = og * 8;

    float acc[8][8];
    #pragma unroll
    for (int i = 0; i < 8; ++i)
        #pragma unroll
        for (int j = 0; j < 8; ++j) acc[i][j] = 0.0f;

    const int lpx = (t & 31) * 4;         // x-stage: float4 along pixels
    const int cst = t >> 5;               // 0..7
    const int ow  = t >> 1;               // w-stage: one hidden channel
    const int cbw = (t & 1) * 16;         // 16 contiguous c per thread

    for (int c0 = 0; c0 < CC; c0 += KC) {
        __syncthreads();
        // stage x tile: 32 c x 128 px (coalesced float4 along hw)
        #pragma unroll
        for (int r = 0; r < 4; ++r) {
            const int c = cst + r * 8;
            const float4 v =
                *(const float4*)&x[(b * CC + c0 + c) * HWP + hw0 + lpx];
            *(float4*)&xs[c * PXT + lpx] = v;
        }
        // stage w1 tile transposed: ws[c][o]
        {
            const float* wrow = &w1[ow * CC + c0 + cbw];
            #pragma unroll
            for (int k = 0; k < 16; k += 4) {
                const float4 wv = *(const float4*)&wrow[k];
                ws[(cbw + k + 0) * CHN + ow] = wv.x;
                ws[(cbw + k + 1) * CHN + ow] = wv.y;
                ws[(cbw + k + 2) * CHN + ow] = wv.z;
                ws[(cbw + k + 3) * CHN + ow] = wv.w;
            }
        }
        __syncthreads();
        #pragma unroll
        for (int c = 0; c < KC; ++c) {
            const float4 xa = *(const float4*)&xs[c * PXT + px0];
            const float4 xb = *(const float4*)&xs[c * PXT + px0 + 4];
            const float4 wa = *(const float4*)&ws[c * CHN + o0];
            const float4 wb = *(const float4*)&ws[c * CHN + o0 + 4];
            const float xv[8] = {xa.x, xa.y, xa.z, xa.w, xb.x, xb.y, xb.z, xb.w};
            const float wv[8] = {wa.x, wa.y, wa.z, wa.w, wb.x, wb.y, wb.z, wb.w};
            #pragma unroll
            for (int i = 0; i < 8; ++i)
                #pragma unroll
                for (int j = 0; j < 8; ++j)
                    acc[i][j] = fmaf(xv[i], wv[j], acc[i][j]);
        }
    }

    // epilogue: bias + ReLU + w2 dot -> per-(pixel, o-group) partial logits
    const float4 b1a = *(const float4*)&b1[o0];
    const float4 b1b = *(const float4*)&b1[o0 + 4];
    const float4 w0a = *(const float4*)&w2[o0];
    const float4 w0b = *(const float4*)&w2[o0 + 4];
    const float4 w1a = *(const float4*)&w2[CHN + o0];
    const float4 w1b = *(const float4*)&w2[CHN + o0 + 4];
    const float bbv[8] = {b1a.x, b1a.y, b1a.z, b1a.w, b1b.x, b1b.y, b1b.z, b1b.w};
    const float w0v[8] = {w0a.x, w0a.y, w0a.z, w0a.w, w0b.x, w0b.y, w0b.z, w0b.w};
    const float w1v[8] = {w1a.x, w1a.y, w1a.z, w1a.w, w1b.x, w1b.y, w1b.z, w1b.w};

    float l0p[8], l1p[8];
    #pragma unroll
    for (int i = 0; i < 8; ++i) {
        float l0 = 0.0f, l1 = 0.0f;
        #pragma unroll
        for (int j = 0; j < 8; ++j) {
            const float h  = acc[i][j] + bbv[j];
            const float rl = fmaxf(h, 0.0f);
            l0 = fmaf(rl, w0v[j], l0);
            l1 = fmaf(rl, w1v[j], l1);
        }
        l0p[i] = l0;
        l1p[i] = l1;
    }

    __syncthreads();  // xs/ws no longer needed; red overlays xs
    #pragma unroll
    for (int i = 0; i < 8; ++i) {
        red[(og * PXT + px0 + i) * 2 + 0] = l0p[i];
        red[(og * PXT + px0 + i) * 2 + 1] = l1p[i];
    }
    __syncthreads();

    if (t < PXT) {
        float l0 = b2[0], l1 = b2[1];
        #pragma unroll
        for (int g = 0; g < 16; ++g) {
            l0 += red[(g * PXT + t) * 2 + 0];
            l1 += red[(g * PXT + t) * 2 + 1];
        }
        // softmax over {l0, l1} (TEMPERATURE == 1)
        const float d  = l1 - l0;
        const float e  = __expf(d);        // d -> +inf: m0 -> 0; -inf: m0 -> 1
        const float m0 = 1.0f / (1.0f + e);
        const float m1 = 1.0f - m0;
        mout[(b * 2 + 0) * HWP + hw0 + t] = m0;
        mout[(b * 2 + 1) * HWP + hw0 + t] = m1;
        sm[t]       = m0;                  // broadcast for phase 3
        sm[PXT + t] = m1;
    }
    __syncthreads();

    // ---- phase 3: x0 = x*m0, x1 = x*m1 for this block's 128 pixels --------
    // Thread t handles pixel-quad lpx2 = (t&31)*4, channel row cr = t>>5,
    // stepping 8 channels/iter. Reverse order: last-staged chunks are the
    // hottest in L2. Nontemporal stores keep writes from evicting x.
    const int lpx2 = (t & 31) * 4;
    const int cr   = t >> 5;              // 0..7
    const v4f m0v = *(const v4f*)&sm[lpx2];
    const v4f m1v = *(const v4f*)&sm[PXT + lpx2];
    const int base = (b * CC) * HWP + hw0 + lpx2;

    #pragma unroll 8
    for (int c0 = CC - 8; c0 >= 0; c0 -= 8) {
        const int idx = base + (c0 + cr) * HWP;
        const v4f xv = *(const v4f*)&x[idx];
        const v4f a0 = xv * m0v;
        const v4f a1 = xv * m1v;
        __builtin_nontemporal_store(a0, (v4f*)&out0[idx]);
        __builtin_nontemporal_store(a1, (v4f*)&out1[idx]);
    }
}

extern "C" void kernel_launch(void* const* d_in, const int* in_sizes, int n_in,
                              void* d_out, int out_size, void* d_ws, size_t ws_size,
                              hipStream_t stream)
{
    const float* x  = (const float*)d_in[0];
    const float* w1 = (const float*)d_in[1];
    const float* b1 = (const float*)d_in[2];
    const float* w2 = (const float*)d_in[3];
    const float* b2 = (const float*)d_in[4];

    float* out  = (float*)d_out;
    float* out0 = out;
    float* out1 = out + (size_t)XSZ;
    float* mo   = out + (size_t)2 * XSZ;

    // 147456 pixels / 128 per block = 1152 blocks
    fused_split_kernel<<<(BB * HWP) / PXT, 256, 0, stream>>>(
        x, w1, b1, w2, b2, out0, out1, mo);
}